// Round 3
// baseline (585.512 us; speedup 1.0000x reference)
//
#include <hip/hip_runtime.h>
#include <hip/hip_bf16.h>
#include <stdint.h>

#define NB 4
#define NS 2048
#define ND 1024
#define NH 16
#define NHS 64
#define NEG_BIG (-1e30f)

typedef __bf16 bf16x8 __attribute__((ext_vector_type(8)));
typedef float floatx4 __attribute__((ext_vector_type(4)));

static constexpr size_t WSLAB = (size_t)NH * ND * NHS;        // 2^20 elems per weight mat
static constexpr size_t QSLAB = (size_t)NB * NH * NS * NHS;   // 8M elems per QKV/Y slab
static constexpr size_t XSLAB = (size_t)NB * NS * ND;         // 8M elems (x as bf16)

__device__ __forceinline__ uint16_t f2b(float f) {
    union { __hip_bfloat16 h; uint16_t u; } cv;
    cv.h = __float2bfloat16(f);
    return cv.u;
}

// ---------------- kernel A: x fp32 -> bf16 ----------------
// 8388608 elems, 8 per thread: grid 4096 x 256
__global__ __launch_bounds__(256) void k_convert_x(
    const float* __restrict__ x, uint16_t* __restrict__ xb) {
  size_t i0 = ((size_t)blockIdx.x * 256 + threadIdx.x) * 8;
  float4 f0 = *(const float4*)&x[i0];
  float4 f1 = *(const float4*)&x[i0 + 4];
  __align__(16) uint16_t tmp[8];
  tmp[0] = f2b(f0.x); tmp[1] = f2b(f0.y); tmp[2] = f2b(f0.z); tmp[3] = f2b(f0.w);
  tmp[4] = f2b(f1.x); tmp[5] = f2b(f1.y); tmp[6] = f2b(f1.z); tmp[7] = f2b(f1.w);
  *(uint4*)&xb[i0] = *(uint4*)tmp;
}

// ---------------- kernel 0: weight convert+transpose (LDS tiled) ----------------
// grid 1024 x 256. blocks 0..767: Wq/Wk/Wv [H,D,HS] -> [H,HS,D]; 768..1023: Wo -> Wo^T
__global__ __launch_bounds__(256) void k_transpose(
    const float* __restrict__ Wq, const float* __restrict__ Wk,
    const float* __restrict__ Wv, const float* __restrict__ Wo,
    uint16_t* __restrict__ ws) {
  __shared__ __align__(16) uint16_t T[64][72];
  int bid = blockIdx.x;
  int tid = threadIdx.x;
  const float* src; uint16_t* dst;
  int srcStride, dstStride, r0, c0;
  if (bid < 768) {
    int mat = bid >> 8;
    int rem = bid & 255;
    int h = rem >> 4, dt = rem & 15;
    const float* W = (mat == 0) ? Wq : (mat == 1) ? Wk : Wv;
    src = W + (size_t)h * (ND * NHS);                 // [1024 x 64] fp32
    dst = ws + (size_t)mat * WSLAB + (size_t)h * (NHS * ND); // [64 x 1024] bf16
    srcStride = NHS; dstStride = ND;
    r0 = dt * 64; c0 = 0;
  } else {
    int rem = bid - 768;
    int dt = rem >> 4, et = rem & 15;
    src = Wo; dst = ws + 3 * WSLAB;
    srcStride = ND; dstStride = ND;
    r0 = dt * 64; c0 = et * 64;
  }
  // load 64x64 fp32 tile, convert to bf16 in LDS
  for (int u = tid; u < 1024; u += 256) {
    int row = u >> 4, cq = u & 15;
    float4 f = *(const float4*)&src[(size_t)(r0 + row) * srcStride + c0 + cq * 4];
    uint16_t* p = &T[row][cq * 4];
    p[0] = f2b(f.x); p[1] = f2b(f.y); p[2] = f2b(f.z); p[3] = f2b(f.w);
  }
  __syncthreads();
  for (int u = tid; u < 512; u += 256) {
    int c = u >> 3, cg = u & 7;
    __align__(16) uint16_t tmp[8];
    for (int j = 0; j < 8; j++) tmp[j] = T[cg * 8 + j][c];
    *(uint4*)&dst[(size_t)(c0 + c) * dstStride + r0 + cg * 8] = *(uint4*)tmp;
  }
}

// ---------------- kernel 1: QKV projection GEMM ----------------
// grid (NS/128, NB*NH, 3), block 256 (4 waves). Each block: 128 rows x 64 cols (one head).
__global__ __launch_bounds__(256) void k_qkv(
    const uint16_t* __restrict__ x, const uint16_t* __restrict__ wt,
    uint16_t* __restrict__ qkv) {
  __shared__ __align__(16) uint16_t As[128][72];
  __shared__ __align__(16) uint16_t Bs[64][72];
  int mat = blockIdx.z;
  int bh = blockIdx.y;
  int b = bh >> 4, h = bh & 15;
  int m0 = blockIdx.x * 128;
  const uint16_t* xb = x + (size_t)b * (NS * ND);
  const uint16_t* wh = wt + (size_t)mat * WSLAB + (size_t)h * (NHS * ND);
  int tid = threadIdx.x;
  int wv = tid >> 6, lane = tid & 63, quad = lane >> 4, l16 = lane & 15;

  floatx4 acc[2][4];
  for (int i = 0; i < 2; i++)
    for (int j = 0; j < 4; j++) acc[i][j] = (floatx4){0.f, 0.f, 0.f, 0.f};

  for (int k0 = 0; k0 < ND; k0 += 64) {
    for (int u = tid; u < 1024; u += 256) {           // A: 128x64
      int row = u >> 3, cg = u & 7;
      *(uint4*)&As[row][cg * 8] =
          *(const uint4*)&xb[(size_t)(m0 + row) * ND + k0 + cg * 8];
    }
    for (int u = tid; u < 512; u += 256) {            // B^T: 64x64
      int row = u >> 3, cg = u & 7;
      *(uint4*)&Bs[row][cg * 8] =
          *(const uint4*)&wh[(size_t)row * ND + k0 + cg * 8];
    }
    __syncthreads();
    for (int kk = 0; kk < 2; kk++) {
      bf16x8 a0 = *(const bf16x8*)&As[wv * 32 + l16][kk * 32 + quad * 8];
      bf16x8 a1 = *(const bf16x8*)&As[wv * 32 + 16 + l16][kk * 32 + quad * 8];
      for (int ct = 0; ct < 4; ct++) {
        bf16x8 bb = *(const bf16x8*)&Bs[ct * 16 + l16][kk * 32 + quad * 8];
        acc[0][ct] = __builtin_amdgcn_mfma_f32_16x16x32_bf16(a0, bb, acc[0][ct], 0, 0, 0);
        acc[1][ct] = __builtin_amdgcn_mfma_f32_16x16x32_bf16(a1, bb, acc[1][ct], 0, 0, 0);
      }
    }
    __syncthreads();
  }
  // write [B,H,S,HS] bf16
  uint16_t* out = qkv + (size_t)mat * QSLAB + (size_t)bh * (NS * NHS);
  for (int rt = 0; rt < 2; rt++)
    for (int ct = 0; ct < 4; ct++)
      for (int r = 0; r < 4; r++) {
        int s = m0 + wv * 32 + rt * 16 + quad * 4 + r;
        int e = ct * 16 + l16;
        out[(size_t)s * NHS + e] = f2b(acc[rt][ct][r]);
      }
}

// ---------------- kernel 2: causal flash attention ----------------
// grid (NS/64, NB*NH), block 256 (4 waves, 16 q-rows each).
__global__ __launch_bounds__(256) void k_attn(
    const uint16_t* __restrict__ Q, const uint16_t* __restrict__ K,
    const uint16_t* __restrict__ V, uint16_t* __restrict__ Y) {
  __shared__ __align__(16) uint16_t Qs[64][72];
  __shared__ __align__(16) uint16_t Ks[64][72];
  __shared__ __align__(16) uint16_t Vt[64][72];     // V transposed: [e][key]
  __shared__ __align__(16) uint16_t Ps[4][16][72];  // per-wave P staging
  int bh = blockIdx.y;
  int b = bh >> 4, h = bh & 15;
  int q0 = blockIdx.x * 64;
  const uint16_t* Qp = Q + (size_t)bh * (NS * NHS);
  const uint16_t* Kp = K + (size_t)bh * (NS * NHS);
  const uint16_t* Vp = V + (size_t)bh * (NS * NHS);
  int tid = threadIdx.x;
  int wv = tid >> 6, lane = tid & 63, quad = lane >> 4, l16 = lane & 15;

  for (int u = tid; u < 512; u += 256) {
    int row = u >> 3, cg = u & 7;
    *(uint4*)&Qs[row][cg * 8] =
        *(const uint4*)&Qp[(size_t)(q0 + row) * NHS + cg * 8];
  }
  __syncthreads();
  bf16x8 aq0 = *(const bf16x8*)&Qs[wv * 16 + l16][quad * 8];
  bf16x8 aq1 = *(const bf16x8*)&Qs[wv * 16 + l16][32 + quad * 8];

  float m_i[4], l_i[4];
  floatx4 o[4];
  for (int r = 0; r < 4; r++) { m_i[r] = NEG_BIG; l_i[r] = 0.f; }
  for (int ct = 0; ct < 4; ct++) o[ct] = (floatx4){0.f, 0.f, 0.f, 0.f};

  int nkt = blockIdx.x + 1;  // causal: key tiles 0..blockIdx.x
  for (int kt = 0; kt < nkt; kt++) {
    __syncthreads();  // previous iter readers done before overwriting Ks/Vt
    for (int u = tid; u < 512; u += 256) {
      int row = u >> 3, cg = u & 7;
      *(uint4*)&Ks[row][cg * 8] =
          *(const uint4*)&Kp[(size_t)(kt * 64 + row) * NHS + cg * 8];
    }
    for (int u = tid; u < 512; u += 256) {
      int row = u >> 3, cg = u & 7;
      uint4 dv = *(const uint4*)&Vp[(size_t)(kt * 64 + row) * NHS + cg * 8];
      const uint16_t* pv = (const uint16_t*)&dv;
      for (int j = 0; j < 8; j++) Vt[cg * 8 + j][row] = pv[j];
    }
    __syncthreads();

    // S = Q K^T * scale, causal mask (finite sentinel, no infinities anywhere)
    floatx4 sf[4];
    for (int ct = 0; ct < 4; ct++) {
      floatx4 c = (floatx4){0.f, 0.f, 0.f, 0.f};
      bf16x8 b0 = *(const bf16x8*)&Ks[ct * 16 + l16][quad * 8];
      bf16x8 b1 = *(const bf16x8*)&Ks[ct * 16 + l16][32 + quad * 8];
      c = __builtin_amdgcn_mfma_f32_16x16x32_bf16(aq0, b0, c, 0, 0, 0);
      c = __builtin_amdgcn_mfma_f32_16x16x32_bf16(aq1, b1, c, 0, 0, 0);
      sf[ct] = c;
    }
    float rmax[4] = {NEG_BIG, NEG_BIG, NEG_BIG, NEG_BIG};
    int qrow_base = q0 + wv * 16 + quad * 4;
    for (int ct = 0; ct < 4; ct++) {
      int kg = kt * 64 + ct * 16 + l16;
      for (int r = 0; r < 4; r++) {
        float v = sf[ct][r] * 0.125f;
        v = (kg <= qrow_base + r) ? v : NEG_BIG;
        sf[ct][r] = v;
        rmax[r] = fmaxf(rmax[r], v);
      }
    }
    for (int off = 1; off < 16; off <<= 1)
      for (int r = 0; r < 4; r++)
        rmax[r] = fmaxf(rmax[r], __shfl_xor(rmax[r], off, 64));
    float alpha[4], m_new[4];
    for (int r = 0; r < 4; r++) {
      m_new[r] = fmaxf(m_i[r], rmax[r]);
      alpha[r] = __expf(m_i[r] - m_new[r]);  // finite-finite; first tile: exp(-huge)=0
      m_i[r] = m_new[r];
    }
    float rsum[4] = {0.f, 0.f, 0.f, 0.f};
    for (int ct = 0; ct < 4; ct++)
      for (int r = 0; r < 4; r++) {
        float p = __expf(sf[ct][r] - m_new[r]);  // masked -> exp(-huge)=0
        sf[ct][r] = p;
        rsum[r] += p;
      }
    for (int off = 1; off < 16; off <<= 1)
      for (int r = 0; r < 4; r++)
        rsum[r] += __shfl_xor(rsum[r], off, 64);
    for (int r = 0; r < 4; r++) l_i[r] = l_i[r] * alpha[r] + rsum[r];
    for (int ct = 0; ct < 4; ct++)
      for (int r = 0; r < 4; r++) o[ct][r] *= alpha[r];

    // P: C-layout -> A-layout via per-wave LDS round-trip (full barrier)
    for (int ct = 0; ct < 4; ct++)
      for (int r = 0; r < 4; r++)
        Ps[wv][quad * 4 + r][ct * 16 + l16] = f2b(sf[ct][r]);
    __syncthreads();
    bf16x8 ap0 = *(const bf16x8*)&Ps[wv][l16][quad * 8];
    bf16x8 ap1 = *(const bf16x8*)&Ps[wv][l16][32 + quad * 8];
    for (int ct = 0; ct < 4; ct++) {
      bf16x8 bv0 = *(const bf16x8*)&Vt[ct * 16 + l16][quad * 8];
      bf16x8 bv1 = *(const bf16x8*)&Vt[ct * 16 + l16][32 + quad * 8];
      o[ct] = __builtin_amdgcn_mfma_f32_16x16x32_bf16(ap0, bv0, o[ct], 0, 0, 0);
      o[ct] = __builtin_amdgcn_mfma_f32_16x16x32_bf16(ap1, bv1, o[ct], 0, 0, 0);
    }
  }
  // epilogue: Y[b, s, h*64 + e] = O / l
  uint16_t* yb = Y + (size_t)b * NS * ND + (size_t)h * NHS;
  for (int ct = 0; ct < 4; ct++)
    for (int r = 0; r < 4; r++) {
      int s = q0 + wv * 16 + quad * 4 + r;
      float val = o[ct][r] / l_i[r];
      yb[(size_t)s * ND + ct * 16 + l16] = f2b(val);
    }
}

// ---------------- kernel 3: output projection + bias (fp32 out) ----------------
// grid (NB*NS/128, ND/64), block 256. Y [8192,1024] @ Wo + bo -> out fp32
__global__ __launch_bounds__(256) void k_proj(
    const uint16_t* __restrict__ y, const uint16_t* __restrict__ wot,
    const float* __restrict__ bo, float* __restrict__ out) {
  __shared__ __align__(16) uint16_t As[128][72];
  __shared__ __align__(16) uint16_t Bs[64][72];
  int m0 = blockIdx.x * 128;
  int n0 = blockIdx.y * 64;
  int tid = threadIdx.x;
  int wv = tid >> 6, lane = tid & 63, quad = lane >> 4, l16 = lane & 15;

  floatx4 acc[2][4];
  for (int i = 0; i < 2; i++)
    for (int j = 0; j < 4; j++) acc[i][j] = (floatx4){0.f, 0.f, 0.f, 0.f};

  for (int k0 = 0; k0 < ND; k0 += 64) {
    for (int u = tid; u < 1024; u += 256) {
      int row = u >> 3, cg = u & 7;
      *(uint4*)&As[row][cg * 8] =
          *(const uint4*)&y[(size_t)(m0 + row) * ND + k0 + cg * 8];
    }
    for (int u = tid; u < 512; u += 256) {
      int row = u >> 3, cg = u & 7;
      *(uint4*)&Bs[row][cg * 8] =
          *(const uint4*)&wot[(size_t)(n0 + row) * ND + k0 + cg * 8];
    }
    __syncthreads();
    for (int kk = 0; kk < 2; kk++) {
      bf16x8 a0 = *(const bf16x8*)&As[wv * 32 + l16][kk * 32 + quad * 8];
      bf16x8 a1 = *(const bf16x8*)&As[wv * 32 + 16 + l16][kk * 32 + quad * 8];
      for (int ct = 0; ct < 4; ct++) {
        bf16x8 bb = *(const bf16x8*)&Bs[ct * 16 + l16][kk * 32 + quad * 8];
        acc[0][ct] = __builtin_amdgcn_mfma_f32_16x16x32_bf16(a0, bb, acc[0][ct], 0, 0, 0);
        acc[1][ct] = __builtin_amdgcn_mfma_f32_16x16x32_bf16(a1, bb, acc[1][ct], 0, 0, 0);
      }
    }
    __syncthreads();
  }
  for (int rt = 0; rt < 2; rt++)
    for (int ct = 0; ct < 4; ct++)
      for (int r = 0; r < 4; r++) {
        int s = m0 + wv * 32 + rt * 16 + quad * 4 + r;
        int n = n0 + ct * 16 + l16;
        out[(size_t)s * ND + n] = acc[rt][ct][r] + bo[n];
      }
}

extern "C" void kernel_launch(void* const* d_in, const int* in_sizes, int n_in,
                              void* d_out, int out_size, void* d_ws, size_t ws_size,
                              hipStream_t stream) {
  const float* x  = (const float*)d_in[0];
  const float* Wq = (const float*)d_in[1];
  const float* Wk = (const float*)d_in[2];
  const float* Wv = (const float*)d_in[3];
  const float* Wo = (const float*)d_in[4];
  const float* bo = (const float*)d_in[5];
  uint16_t* ws = (uint16_t*)d_ws;

  uint16_t* wt = ws;                       // 4 * WSLAB (Wq_t, Wk_t, Wv_t, Wo_t) bf16
  uint16_t* xb = ws + 4 * WSLAB;           // XSLAB bf16
  uint16_t* q  = xb + XSLAB;               // QSLAB each
  uint16_t* k  = q + QSLAB;
  uint16_t* v  = k + QSLAB;
  uint16_t* y  = v + QSLAB;

  k_convert_x<<<dim3(XSLAB / (256 * 8)), dim3(256), 0, stream>>>(x, xb);
  k_transpose<<<dim3(1024), dim3(256), 0, stream>>>(Wq, Wk, Wv, Wo, wt);
  k_qkv<<<dim3(NS / 128, NB * NH, 3), dim3(256), 0, stream>>>(xb, wt, q);
  k_attn<<<dim3(NS / 64, NB * NH), dim3(256), 0, stream>>>(q, k, v, y);
  k_proj<<<dim3(NB * NS / 128, ND / 64), dim3(256), 0, stream>>>(y, wt + 3 * WSLAB, bo, (float*)d_out);
}

// Round 4
// 448.403 us; speedup vs baseline: 1.3058x; 1.3058x over previous
//
#include <hip/hip_runtime.h>
#include <hip/hip_bf16.h>
#include <stdint.h>

#define NB 4
#define NS 2048
#define ND 1024
#define NH 16
#define NHS 64
#define NEG_BIG (-1e30f)

typedef __bf16 bf16x8 __attribute__((ext_vector_type(8)));
typedef float floatx4 __attribute__((ext_vector_type(4)));

static constexpr size_t WSLAB = (size_t)NH * ND * NHS;        // 2^20 elems per weight mat
static constexpr size_t QSLAB = (size_t)NB * NH * NS * NHS;   // 8M elems per QKV/Y slab
static constexpr size_t XSLAB = (size_t)NB * NS * ND;         // 8M elems (x as bf16)

__device__ __forceinline__ uint16_t f2b(float f) {
    union { __hip_bfloat16 h; uint16_t u; } cv;
    cv.h = __float2bfloat16(f);
    return cv.u;
}

// ---------------- kernel A: x fp32 -> bf16 ----------------
__global__ __launch_bounds__(256) void k_convert_x(
    const float* __restrict__ x, uint16_t* __restrict__ xb) {
  size_t i0 = ((size_t)blockIdx.x * 256 + threadIdx.x) * 8;
  float4 f0 = *(const float4*)&x[i0];
  float4 f1 = *(const float4*)&x[i0 + 4];
  __align__(16) uint16_t tmp[8];
  tmp[0] = f2b(f0.x); tmp[1] = f2b(f0.y); tmp[2] = f2b(f0.z); tmp[3] = f2b(f0.w);
  tmp[4] = f2b(f1.x); tmp[5] = f2b(f1.y); tmp[6] = f2b(f1.z); tmp[7] = f2b(f1.w);
  *(uint4*)&xb[i0] = *(uint4*)tmp;
}

// ---------------- kernel 0: weight convert+transpose (LDS tiled) ----------------
__global__ __launch_bounds__(256) void k_transpose(
    const float* __restrict__ Wq, const float* __restrict__ Wk,
    const float* __restrict__ Wv, const float* __restrict__ Wo,
    uint16_t* __restrict__ ws) {
  __shared__ __align__(16) uint16_t T[64][72];
  int bid = blockIdx.x;
  int tid = threadIdx.x;
  const float* src; uint16_t* dst;
  int srcStride, dstStride, r0, c0;
  if (bid < 768) {
    int mat = bid >> 8;
    int rem = bid & 255;
    int h = rem >> 4, dt = rem & 15;
    const float* W = (mat == 0) ? Wq : (mat == 1) ? Wk : Wv;
    src = W + (size_t)h * (ND * NHS);
    dst = ws + (size_t)mat * WSLAB + (size_t)h * (NHS * ND);
    srcStride = NHS; dstStride = ND;
    r0 = dt * 64; c0 = 0;
  } else {
    int rem = bid - 768;
    int dt = rem >> 4, et = rem & 15;
    src = Wo; dst = ws + 3 * WSLAB;
    srcStride = ND; dstStride = ND;
    r0 = dt * 64; c0 = et * 64;
  }
  for (int u = tid; u < 1024; u += 256) {
    int row = u >> 4, cq = u & 15;
    float4 f = *(const float4*)&src[(size_t)(r0 + row) * srcStride + c0 + cq * 4];
    uint16_t* p = &T[row][cq * 4];
    p[0] = f2b(f.x); p[1] = f2b(f.y); p[2] = f2b(f.z); p[3] = f2b(f.w);
  }
  __syncthreads();
  for (int u = tid; u < 512; u += 256) {
    int c = u >> 3, cg = u & 7;
    __align__(16) uint16_t tmp[8];
    for (int j = 0; j < 8; j++) tmp[j] = T[cg * 8 + j][c];
    *(uint4*)&dst[(size_t)(c0 + c) * dstStride + r0 + cg * 8] = *(uint4*)tmp;
  }
}

// ---------------- kernel 1: QKV projection GEMM (Q pre-scaled by 1/8) ----------------
__global__ __launch_bounds__(256) void k_qkv(
    const uint16_t* __restrict__ x, const uint16_t* __restrict__ wt,
    uint16_t* __restrict__ qkv) {
  __shared__ __align__(16) uint16_t As[128][72];
  __shared__ __align__(16) uint16_t Bs[64][72];
  int mat = blockIdx.z;
  int bh = blockIdx.y;
  int b = bh >> 4, h = bh & 15;
  int m0 = blockIdx.x * 128;
  const uint16_t* xb = x + (size_t)b * (NS * ND);
  const uint16_t* wh = wt + (size_t)mat * WSLAB + (size_t)h * (NHS * ND);
  int tid = threadIdx.x;
  int wv = tid >> 6, lane = tid & 63, quad = lane >> 4, l16 = lane & 15;

  floatx4 acc[2][4];
  for (int i = 0; i < 2; i++)
    for (int j = 0; j < 4; j++) acc[i][j] = (floatx4){0.f, 0.f, 0.f, 0.f};

  for (int k0 = 0; k0 < ND; k0 += 64) {
    for (int u = tid; u < 1024; u += 256) {
      int row = u >> 3, cg = u & 7;
      *(uint4*)&As[row][cg * 8] =
          *(const uint4*)&xb[(size_t)(m0 + row) * ND + k0 + cg * 8];
    }
    for (int u = tid; u < 512; u += 256) {
      int row = u >> 3, cg = u & 7;
      *(uint4*)&Bs[row][cg * 8] =
          *(const uint4*)&wh[(size_t)row * ND + k0 + cg * 8];
    }
    __syncthreads();
    for (int kk = 0; kk < 2; kk++) {
      bf16x8 a0 = *(const bf16x8*)&As[wv * 32 + l16][kk * 32 + quad * 8];
      bf16x8 a1 = *(const bf16x8*)&As[wv * 32 + 16 + l16][kk * 32 + quad * 8];
      for (int ct = 0; ct < 4; ct++) {
        bf16x8 bb = *(const bf16x8*)&Bs[ct * 16 + l16][kk * 32 + quad * 8];
        acc[0][ct] = __builtin_amdgcn_mfma_f32_16x16x32_bf16(a0, bb, acc[0][ct], 0, 0, 0);
        acc[1][ct] = __builtin_amdgcn_mfma_f32_16x16x32_bf16(a1, bb, acc[1][ct], 0, 0, 0);
      }
    }
    __syncthreads();
  }
  float scale = (mat == 0) ? 0.125f : 1.0f;  // fold 1/sqrt(HS) into Q (exact pow2)
  uint16_t* out = qkv + (size_t)mat * QSLAB + (size_t)bh * (NS * NHS);
  for (int rt = 0; rt < 2; rt++)
    for (int ct = 0; ct < 4; ct++)
      for (int r = 0; r < 4; r++) {
        int s = m0 + wv * 32 + rt * 16 + quad * 4 + r;
        int e = ct * 16 + l16;
        out[(size_t)s * NHS + e] = f2b(acc[rt][ct][r] * scale);
      }
}

// ---------------- kernel 1b: V -> V^T ([B,H,S,HS] -> [B,H,HS,S]) ----------------
// grid (NS/64, NB*NH)
__global__ __launch_bounds__(256) void k_vt(
    const uint16_t* __restrict__ v, uint16_t* __restrict__ vt) {
  __shared__ __align__(16) uint16_t T[64][72];
  int bh = blockIdx.y;
  int s0 = blockIdx.x * 64;
  int tid = threadIdx.x;
  const uint16_t* src = v + (size_t)bh * (NS * NHS);
  uint16_t* dst = vt + (size_t)bh * (NS * NHS);
  for (int u = tid; u < 512; u += 256) {
    int row = u >> 3, cg = u & 7;
    *(uint4*)&T[row][cg * 8] =
        *(const uint4*)&src[(size_t)(s0 + row) * NHS + cg * 8];
  }
  __syncthreads();
  for (int u = tid; u < 512; u += 256) {
    int e = u >> 3, cg = u & 7;
    __align__(16) uint16_t tmp[8];
    for (int j = 0; j < 8; j++) tmp[j] = T[cg * 8 + j][e];
    *(uint4*)&dst[(size_t)e * NS + s0 + cg * 8] = *(uint4*)tmp;
  }
}

// ---------------- kernel 2: causal flash attention, paired q-tiles ----------------
// grid (16, NB*NH), block 256 (4 waves). Block handles q-tiles ta=blockIdx.x and
// tb=31-ta (uniform 33 compute-tiles/block). K/V^T staging shared between tiles.
__global__ __launch_bounds__(256) void k_attn(
    const uint16_t* __restrict__ Q, const uint16_t* __restrict__ K,
    const uint16_t* __restrict__ VT, uint16_t* __restrict__ Y) {
  __shared__ __align__(16) uint16_t Ks[64][72];
  __shared__ __align__(16) uint16_t Vs[64][72];     // V^T tile: [e][key]
  __shared__ __align__(16) uint16_t Ps[4][16][72];  // per-wave P staging
  int bh = blockIdx.y;
  int b = bh >> 4, h = bh & 15;
  int ta = blockIdx.x;       // 0..15
  int tb = 31 - ta;          // 16..31
  const uint16_t* Qp = Q + (size_t)bh * (NS * NHS);
  const uint16_t* Kp = K + (size_t)bh * (NS * NHS);
  const uint16_t* Vp = VT + (size_t)bh * (NS * NHS);
  int tid = threadIdx.x;
  int wv = tid >> 6, lane = tid & 63, quad = lane >> 4, l16 = lane & 15;

  // Q fragments straight from global (A-layout: m=l16 row, k=quad*8+j)
  int rA = ta * 64 + wv * 16 + l16;
  int rB = tb * 64 + wv * 16 + l16;
  bf16x8 aqA0 = *(const bf16x8*)&Qp[(size_t)rA * NHS + quad * 8];
  bf16x8 aqA1 = *(const bf16x8*)&Qp[(size_t)rA * NHS + 32 + quad * 8];
  bf16x8 aqB0 = *(const bf16x8*)&Qp[(size_t)rB * NHS + quad * 8];
  bf16x8 aqB1 = *(const bf16x8*)&Qp[(size_t)rB * NHS + 32 + quad * 8];

  float mA[4], lA[4], mB[4], lB[4];
  floatx4 oA[4], oB[4];
  for (int r = 0; r < 4; r++) { mA[r] = NEG_BIG; lA[r] = 0.f; mB[r] = NEG_BIG; lB[r] = 0.f; }
  for (int ct = 0; ct < 4; ct++) {
    oA[ct] = (floatx4){0.f, 0.f, 0.f, 0.f};
    oB[ct] = (floatx4){0.f, 0.f, 0.f, 0.f};
  }

  int kt = 0;
  auto process = [&](bf16x8 a0, bf16x8 a1, int tq, float* m_i, float* l_i, floatx4* o) {
    floatx4 sf[4];
    for (int ct = 0; ct < 4; ct++) {
      floatx4 c = (floatx4){0.f, 0.f, 0.f, 0.f};
      bf16x8 b0 = *(const bf16x8*)&Ks[ct * 16 + l16][quad * 8];
      bf16x8 b1 = *(const bf16x8*)&Ks[ct * 16 + l16][32 + quad * 8];
      c = __builtin_amdgcn_mfma_f32_16x16x32_bf16(a0, b0, c, 0, 0, 0);
      c = __builtin_amdgcn_mfma_f32_16x16x32_bf16(a1, b1, c, 0, 0, 0);
      sf[ct] = c;
    }
    if (kt == tq) {  // diagonal tile: causal mask (wave-uniform branch)
      int qrb = tq * 64 + wv * 16 + quad * 4;
      for (int ct = 0; ct < 4; ct++) {
        int kg = kt * 64 + ct * 16 + l16;
        for (int r = 0; r < 4; r++)
          sf[ct][r] = (kg <= qrb + r) ? sf[ct][r] : NEG_BIG;
      }
    }
    float rmax[4] = {NEG_BIG, NEG_BIG, NEG_BIG, NEG_BIG};
    for (int ct = 0; ct < 4; ct++)
      for (int r = 0; r < 4; r++) rmax[r] = fmaxf(rmax[r], sf[ct][r]);
    for (int off = 1; off < 16; off <<= 1)
      for (int r = 0; r < 4; r++)
        rmax[r] = fmaxf(rmax[r], __shfl_xor(rmax[r], off, 64));
    float alpha[4], m_new[4];
    for (int r = 0; r < 4; r++) {
      m_new[r] = fmaxf(m_i[r], rmax[r]);
      alpha[r] = __expf(m_i[r] - m_new[r]);
      m_i[r] = m_new[r];
    }
    float rsum[4] = {0.f, 0.f, 0.f, 0.f};
    for (int ct = 0; ct < 4; ct++)
      for (int r = 0; r < 4; r++) {
        float p = __expf(sf[ct][r] - m_new[r]);
        sf[ct][r] = p;
        rsum[r] += p;
      }
    for (int off = 1; off < 16; off <<= 1)
      for (int r = 0; r < 4; r++)
        rsum[r] += __shfl_xor(rsum[r], off, 64);
    for (int r = 0; r < 4; r++) l_i[r] = l_i[r] * alpha[r] + rsum[r];
    for (int ct = 0; ct < 4; ct++)
      for (int r = 0; r < 4; r++) o[ct][r] *= alpha[r];
    // P: C-layout -> A-layout, per-wave LDS round trip (same-wave ordering only)
    for (int ct = 0; ct < 4; ct++)
      for (int r = 0; r < 4; r++)
        Ps[wv][quad * 4 + r][ct * 16 + l16] = f2b(sf[ct][r]);
    bf16x8 ap0 = *(const bf16x8*)&Ps[wv][l16][quad * 8];
    bf16x8 ap1 = *(const bf16x8*)&Ps[wv][l16][32 + quad * 8];
    for (int ct = 0; ct < 4; ct++) {
      bf16x8 bv0 = *(const bf16x8*)&Vs[ct * 16 + l16][quad * 8];
      bf16x8 bv1 = *(const bf16x8*)&Vs[ct * 16 + l16][32 + quad * 8];
      o[ct] = __builtin_amdgcn_mfma_f32_16x16x32_bf16(ap0, bv0, o[ct], 0, 0, 0);
      o[ct] = __builtin_amdgcn_mfma_f32_16x16x32_bf16(ap1, bv1, o[ct], 0, 0, 0);
    }
  };

  for (kt = 0; kt <= tb; kt++) {
    __syncthreads();  // prior readers of Ks/Vs done
    for (int u = tid; u < 512; u += 256) {
      int row = u >> 3, cg = u & 7;
      *(uint4*)&Ks[row][cg * 8] =
          *(const uint4*)&Kp[(size_t)(kt * 64 + row) * NHS + cg * 8];
    }
    for (int u = tid; u < 512; u += 256) {
      int row = u >> 3, cg = u & 7;   // row = e, cols = keys
      *(uint4*)&Vs[row][cg * 8] =
          *(const uint4*)&Vp[(size_t)row * NS + kt * 64 + cg * 8];
    }
    __syncthreads();
    process(aqB0, aqB1, tb, mB, lB, oB);
    if (kt <= ta) process(aqA0, aqA1, ta, mA, lA, oA);
  }

  uint16_t* yb = Y + (size_t)b * NS * ND + (size_t)h * NHS;
  for (int ct = 0; ct < 4; ct++)
    for (int r = 0; r < 4; r++) {
      int sA = ta * 64 + wv * 16 + quad * 4 + r;
      int sB = tb * 64 + wv * 16 + quad * 4 + r;
      yb[(size_t)sA * ND + ct * 16 + l16] = f2b(oA[ct][r] / lA[r]);
      yb[(size_t)sB * ND + ct * 16 + l16] = f2b(oB[ct][r] / lB[r]);
    }
}

// ---------------- kernel 3: output projection + bias (fp32 out) ----------------
__global__ __launch_bounds__(256) void k_proj(
    const uint16_t* __restrict__ y, const uint16_t* __restrict__ wot,
    const float* __restrict__ bo, float* __restrict__ out) {
  __shared__ __align__(16) uint16_t As[128][72];
  __shared__ __align__(16) uint16_t Bs[64][72];
  int m0 = blockIdx.x * 128;
  int n0 = blockIdx.y * 64;
  int tid = threadIdx.x;
  int wv = tid >> 6, lane = tid & 63, quad = lane >> 4, l16 = lane & 15;

  floatx4 acc[2][4];
  for (int i = 0; i < 2; i++)
    for (int j = 0; j < 4; j++) acc[i][j] = (floatx4){0.f, 0.f, 0.f, 0.f};

  for (int k0 = 0; k0 < ND; k0 += 64) {
    for (int u = tid; u < 1024; u += 256) {
      int row = u >> 3, cg = u & 7;
      *(uint4*)&As[row][cg * 8] =
          *(const uint4*)&y[(size_t)(m0 + row) * ND + k0 + cg * 8];
    }
    for (int u = tid; u < 512; u += 256) {
      int row = u >> 3, cg = u & 7;
      *(uint4*)&Bs[row][cg * 8] =
          *(const uint4*)&wot[(size_t)(n0 + row) * ND + k0 + cg * 8];
    }
    __syncthreads();
    for (int kk = 0; kk < 2; kk++) {
      bf16x8 a0 = *(const bf16x8*)&As[wv * 32 + l16][kk * 32 + quad * 8];
      bf16x8 a1 = *(const bf16x8*)&As[wv * 32 + 16 + l16][kk * 32 + quad * 8];
      for (int ct = 0; ct < 4; ct++) {
        bf16x8 bb = *(const bf16x8*)&Bs[ct * 16 + l16][kk * 32 + quad * 8];
        acc[0][ct] = __builtin_amdgcn_mfma_f32_16x16x32_bf16(a0, bb, acc[0][ct], 0, 0, 0);
        acc[1][ct] = __builtin_amdgcn_mfma_f32_16x16x32_bf16(a1, bb, acc[1][ct], 0, 0, 0);
      }
    }
    __syncthreads();
  }
  for (int rt = 0; rt < 2; rt++)
    for (int ct = 0; ct < 4; ct++)
      for (int r = 0; r < 4; r++) {
        int s = m0 + wv * 32 + rt * 16 + quad * 4 + r;
        int n = n0 + ct * 16 + l16;
        out[(size_t)s * ND + n] = acc[rt][ct][r] + bo[n];
      }
}

extern "C" void kernel_launch(void* const* d_in, const int* in_sizes, int n_in,
                              void* d_out, int out_size, void* d_ws, size_t ws_size,
                              hipStream_t stream) {
  const float* x  = (const float*)d_in[0];
  const float* Wq = (const float*)d_in[1];
  const float* Wk = (const float*)d_in[2];
  const float* Wv = (const float*)d_in[3];
  const float* Wo = (const float*)d_in[4];
  const float* bo = (const float*)d_in[5];
  uint16_t* ws = (uint16_t*)d_ws;

  uint16_t* wt = ws;                       // 4 * WSLAB bf16 (Wq_t, Wk_t, Wv_t, Wo_t)
  uint16_t* xb = ws + 4 * WSLAB;           // XSLAB bf16
  uint16_t* q  = xb + XSLAB;               // QSLAB each
  uint16_t* k  = q + QSLAB;
  uint16_t* v  = k + QSLAB;
  uint16_t* y  = v + QSLAB;
  uint16_t* vt = y + QSLAB;                // QSLAB (V transposed)

  k_convert_x<<<dim3(XSLAB / (256 * 8)), dim3(256), 0, stream>>>(x, xb);
  k_transpose<<<dim3(1024), dim3(256), 0, stream>>>(Wq, Wk, Wv, Wo, wt);
  k_qkv<<<dim3(NS / 128, NB * NH, 3), dim3(256), 0, stream>>>(xb, wt, q);
  k_vt<<<dim3(NS / 64, NB * NH), dim3(256), 0, stream>>>(v, vt);
  k_attn<<<dim3(16, NB * NH), dim3(256), 0, stream>>>(q, k, vt, y);
  k_proj<<<dim3(NB * NS / 128, ND / 64), dim3(256), 0, stream>>>(y, wt + 3 * WSLAB, bo, (float*)d_out);
}